// Round 1
// baseline (1306.572 us; speedup 1.0000x reference)
//
#include <hip/hip_runtime.h>

// FiberConv: out[b, t*OUT+o] = sum_{s,i} kernel[t,s,o,i] * x[b, s*IN+i] + bias[o]
// kernel[t,s,o,i] = sum_a edge[t,s,a] * W[o*IN+i, a]
// => GEMM: X[400000 x 384] * Bmat^T where Bmat[n=t*32+o][k=s*32+i], all f32 I/O,
//    bf16 MFMA internally (harness threshold 2.7 admits bf16).

using f32x4  = __attribute__((ext_vector_type(4))) float;
using bf16x8 = __attribute__((ext_vector_type(8))) __bf16;
using short8 = __attribute__((ext_vector_type(8))) short;

constexpr int T_   = 12;
constexpr int S_   = 12;
constexpr int ATTR = 3;
constexpr int IN   = 32;
constexpr int OUT  = 32;
constexpr int K    = S_ * IN;    // 384
constexpr int N    = T_ * OUT;   // 384
constexpr int NB   = 400000;     // batch rows
constexpr int KB_CNT = K / 32;   // 12 K-chunks per MFMA K=32
constexpr int NT_CNT = N / 16;   // 24 N-tiles of 16

__device__ __forceinline__ unsigned short f2bf(float f) {
  // round-to-nearest-even f32 -> bf16 (inputs are finite normals)
  unsigned u = __builtin_bit_cast(unsigned, f);
  u += 0x7fffu + ((u >> 16) & 1u);
  return (unsigned short)(u >> 16);
}

// Build Bmat[n][k] in bf16: n = t*32+o, k = s*32+i. 384 blocks x 384 threads.
__global__ __launch_bounds__(384) void build_B(const float* __restrict__ edge,
                                               const float* __restrict__ W,
                                               unsigned short* __restrict__ Bm) {
  const int n = blockIdx.x;   // 0..383
  const int k = threadIdx.x;  // 0..383
  const int t = n >> 5, o = n & 31;
  const int s = k >> 5, i = k & 31;
  const float* e = edge + (t * S_ + s) * ATTR;
  const float* w = W + (o * IN + i) * ATTR;
  const float v = e[0] * w[0] + e[1] * w[1] + e[2] * w[2];
  Bm[n * K + k] = f2bf(v);
}

// 4 waves/block, 32 rows/wave (2 M-tiles), full N=384 per wave.
// A fragments (whole K) persist in registers; B fragments stream from L1/L2.
__global__ __launch_bounds__(256, 2) void fiber_gemm(
    const float* __restrict__ x, const unsigned short* __restrict__ Bm,
    const float* __restrict__ bias, float* __restrict__ out) {
  const int lane = threadIdx.x & 63;
  const int wid  = threadIdx.x >> 6;
  const int col  = lane & 15;   // MFMA 16-dim index (M for A, N for B/C)
  const int quad = lane >> 4;   // K-subchunk / C-row-group index
  const int rowbase = blockIdx.x * 128 + wid * 32;  // 3125*128 = 400000 exact

  // ---- Load + convert all A fragments: A[mt][kb] covers rows rowbase+mt*16+col,
  //      k in [kb*32 + quad*8, +8). Layout: A[m=lane&15][k=quad*8+j].
  bf16x8 A[2][KB_CNT];
#pragma unroll
  for (int mt = 0; mt < 2; ++mt) {
    const float* xp = x + (rowbase + mt * 16 + col) * K + quad * 8;
#pragma unroll
    for (int kb = 0; kb < KB_CNT; ++kb) {
      const f32x4 lo = *(const f32x4*)(xp + kb * 32);
      const f32x4 hi = *(const f32x4*)(xp + kb * 32 + 4);
      short8 sv;
#pragma unroll
      for (int j = 0; j < 4; ++j) {
        sv[j]     = (short)f2bf(lo[j]);
        sv[j + 4] = (short)f2bf(hi[j]);
      }
      A[mt][kb] = __builtin_bit_cast(bf16x8, sv);
    }
  }

  // ---- N-tile loop: 12 MFMA K-steps x 2 M-tiles each, then store.
#pragma unroll 1
  for (int nt = 0; nt < NT_CNT; ++nt) {
    const unsigned short* bp = Bm + (nt * 16 + col) * K + quad * 8;
    f32x4 acc0 = {0.f, 0.f, 0.f, 0.f};
    f32x4 acc1 = {0.f, 0.f, 0.f, 0.f};
#pragma unroll
    for (int kb = 0; kb < KB_CNT; ++kb) {
      const bf16x8 Bf = *(const bf16x8*)(bp + kb * 32);
      acc0 = __builtin_amdgcn_mfma_f32_16x16x32_bf16(A[0][kb], Bf, acc0, 0, 0, 0);
      acc1 = __builtin_amdgcn_mfma_f32_16x16x32_bf16(A[1][kb], Bf, acc1, 0, 0, 0);
    }
    // C/D layout: col = lane&15 (N), row = quad*4 + r (M within 16-tile)
    const float bv = bias[(nt * 16 + col) & 31];
    float* op = out + (rowbase + quad * 4) * N + nt * 16 + col;
#pragma unroll
    for (int r = 0; r < 4; ++r) {
      op[r * N]        = acc0[r] + bv;  // M-tile 0: rows rowbase + quad*4 + r
      op[(16 + r) * N] = acc1[r] + bv;  // M-tile 1: rows rowbase + 16 + quad*4 + r
    }
  }
}

extern "C" void kernel_launch(void* const* d_in, const int* in_sizes, int n_in,
                              void* d_out, int out_size, void* d_ws, size_t ws_size,
                              hipStream_t stream) {
  const float* x    = (const float*)d_in[0];  // [B, S, IN] f32
  const float* edge = (const float*)d_in[1];  // [T, S, ATTR] f32
  const float* W    = (const float*)d_in[2];  // [OUT*IN, ATTR] f32
  const float* bias = (const float*)d_in[3];  // [OUT] f32
  float* out = (float*)d_out;                 // [B, T, OUT] f32
  unsigned short* Bm = (unsigned short*)d_ws; // 384*384 bf16 = 294912 B scratch

  build_B<<<dim3(N), dim3(K), 0, stream>>>(edge, W, Bm);
  fiber_gemm<<<dim3(NB / 128), dim3(256), 0, stream>>>(x, Bm, bias, out);
}